// Round 11
// baseline (212.597 us; speedup 1.0000x reference)
//
#include <hip/hip_runtime.h>
#include <hip/hip_bf16.h>
#include <stdint.h>

typedef unsigned short ushort_t;
using short8   = __attribute__((ext_vector_type(8))) short;
using float4v  = __attribute__((ext_vector_type(4))) float;

#define BSH    6          // bucket = 64 consecutive dst nodes
#define BUCKW  64
#define CAP    1536       // per-bucket capacity (avg 1024, +16 sigma)
#define NBMAX  2048
#define HPITCH 136        // h_s row pitch (ushorts)
#define APITCH 72         // agg_s row pitch (ushorts): dword-pitch 36 -> 2-way banks

__device__ __forceinline__ float bf2f(ushort_t u) {
    union { unsigned int i; float f; } v;
    v.i = ((unsigned int)u) << 16;
    return v.f;
}
__device__ __forceinline__ ushort_t f2b(float f) {
    union { float f; unsigned int i; } v;
    v.f = f;
    unsigned int u = v.i;
    unsigned int r = (u + 0x7fffu + ((u >> 16) & 1u)) >> 16;   // RNE
    return (ushort_t)r;
}
__device__ __forceinline__ float blo2f(unsigned v) {
    union { unsigned i; float f; } u; u.i = v << 16; return u.f;
}
__device__ __forceinline__ float bhi2f(unsigned v) {
    union { unsigned i; float f; } u; u.i = v & 0xFFFF0000u; return u.f;
}

// ---------------------------------------------------------------------------
// Transpose inp [64][N] fp32 -> X [N][64] bf16 (staged in d_out; consumed by
// baggmlp_k before it overwrites d_out). Block 0 also converts weights to
// bf16 and inits per-bucket cursors (absolute: gcur[b] = b*CAP).
// ---------------------------------------------------------------------------
__global__ void transpose_k(const float* __restrict__ inp,
                            ushort_t* __restrict__ X, int N,
                            const float* __restrict__ W1,
                            const float* __restrict__ W2,
                            ushort_t* __restrict__ w1b,
                            ushort_t* __restrict__ w2b,
                            int* __restrict__ gcur, int NB) {
    if (blockIdx.x == 0) {
        for (int i = threadIdx.x; i < 8192; i += 256) {
            w1b[i] = f2b(W1[i]);
            w2b[i] = f2b(W2[i]);
        }
        for (int b = threadIdx.x; b < NB; b += 256) gcur[b] = b * CAP;
    }
    __shared__ float tile[64][65];
    int tx = threadIdx.x & 63;
    int ty = threadIdx.x >> 6;
    int n0 = blockIdx.x * 64;
#pragma unroll
    for (int r = 0; r < 16; ++r) {
        int d = ty * 16 + r;
        int n = n0 + tx;
        if (n < N) tile[d][tx] = inp[(size_t)d * N + n];
    }
    __syncthreads();
#pragma unroll
    for (int r = 0; r < 16; ++r) {
        int nl = ty * 16 + r;
        int n  = n0 + nl;
        if (n < N) X[(size_t)n * 64 + tx] = f2b(tile[tx][nl]);
    }
}

// ---------------------------------------------------------------------------
// Two-sweep binning (block-private spans => same-block line ownership =>
// coalesced L2 write-back). 128 blocks x 1024 threads.
// ---------------------------------------------------------------------------
__global__ __launch_bounds__(1024) void bin_k(
        const int* __restrict__ src, const int* __restrict__ dst,
        int* __restrict__ gcur, unsigned* __restrict__ bin, int E, int NB) {
    __shared__ int lcnt[NBMAX];
    __shared__ int gbase[NBMAX];
    __shared__ int lcur[NBMAX];
    int tid   = threadIdx.x;
    int chunk = (E + gridDim.x - 1) / gridDim.x;
    int s0 = blockIdx.x * chunk;
    int s1 = s0 + chunk;
    if (s1 > E) s1 = E;

    for (int b = tid; b < NB; b += 1024) lcnt[b] = 0;
    __syncthreads();

    for (int e = s0 + tid; e < s1; e += 1024)
        atomicAdd(&lcnt[dst[e] >> BSH], 1);
    __syncthreads();

    for (int b = tid; b < NB; b += 1024) {
        int c = lcnt[b];
        gbase[b] = c ? atomicAdd(&gcur[b], c) : 0;
        lcur[b]  = 0;
    }
    __syncthreads();

    for (int e = s0 + tid; e < s1; e += 1024) {
        int d = dst[e];
        int b = d >> BSH;
        int pos = gbase[b] + atomicAdd(&lcur[b], 1);
        if (pos < (b + 1) * CAP)   // overflow guard (statistically unreachable)
            bin[pos] = ((unsigned)(d & (BUCKW - 1)) << 24) | (unsigned)src[e];
    }
}

// ---------------------------------------------------------------------------
// FUSED aggregation + MLP. Block b owns nodes [b*64, b*64+64).
// Phase 1 (gather): counting-sort bucket edges in LDS, one wave per node,
//   dword-pair gather (lanes 0-31 = edge e row, lanes 32-63 = edge e+1 row;
//   16 edges in flight at unroll 8), agg -> LDS bf16 tile (pitch 72).
// Phase 2 (MLP): same 256 threads run the 2-layer MFMA MLP on the 64 nodes,
//   A-fragments via ds_read_b128 from agg tile (2-way banks = free).
// Kills: one dispatch, agg 12.8MB write + 12.8MB read, mlp A-frag fetch.
// LDS: agg 9216 + max(sort 6912, h_s 17408) = 26624 B => 6 blocks/CU.
// ---------------------------------------------------------------------------
__global__ __launch_bounds__(256) void baggmlp_k(
        const unsigned* __restrict__ Xu, const unsigned* __restrict__ bin,
        const int* __restrict__ gcur,
        const ushort_t* __restrict__ W1, const float* __restrict__ b1,
        const ushort_t* __restrict__ W2, const float* __restrict__ b2,
        float* __restrict__ out, int N) {
    __shared__ __align__(16) ushort_t agg_s[BUCKW * APITCH];   // 9216 B
    __shared__ __align__(16) char scratch[4 * 16 * HPITCH * 2]; // 17408 B
    unsigned* sl   = (unsigned*)scratch;                 // phase 1
    int*      ecnt = (int*)(scratch + CAP * 4);
    int*      sc   = ecnt + BUCKW;
    int*      ecur = sc + BUCKW;
    ushort_t* h_s  = (ushort_t*)scratch;                 // phase 2 (reuse)

    int tid = threadIdx.x;
    int b   = blockIdx.x;
    int lo  = b << BSH;

    // ---- Phase 1: sort + gather ----
    int cnt = gcur[b] - b * CAP;
    if (cnt > CAP) cnt = CAP;
    const unsigned* bb = bin + (size_t)b * CAP;

    if (tid < BUCKW) ecnt[tid] = 0;
    for (int i = tid; i < BUCKW * (APITCH / 2); i += 256)
        ((unsigned*)agg_s)[i] = 0;                       // zero agg tile
    __syncthreads();

    for (int i = tid; i < cnt; i += 256)
        atomicAdd(&ecnt[bb[i] >> 24], 1);
    __syncthreads();

    if (tid < BUCKW) sc[tid] = ecnt[tid];
    __syncthreads();
#pragma unroll
    for (int off = 1; off < BUCKW; off <<= 1) {
        int v = 0;
        if (tid < BUCKW && tid >= off) v = sc[tid - off];
        __syncthreads();
        if (tid < BUCKW) sc[tid] += v;
        __syncthreads();
    }
    if (tid < BUCKW) { sc[tid] -= ecnt[tid]; ecur[tid] = 0; }   // exclusive
    __syncthreads();

    for (int i = tid; i < cnt; i += 256) {
        unsigned p = bb[i];
        int nl  = (int)(p >> 24);
        int pos = sc[nl] + atomicAdd(&ecur[nl], 1);
        sl[pos] = p;
    }
    __syncthreads();

    int wave = tid >> 6;               // 0..3
    int lane = tid & 63;
    int half = lane >> 5;              // 0: even edges, 1: odd edges
    int c2   = lane & 31;              // dword index within row (2 dims)

    for (int n = wave; n < BUCKW; n += 4) {
        int node = lo + n;
        if (node >= N) break;
        int s0 = sc[n];
        int c  = ecnt[n];
        float alo0 = 0.f, ahi0 = 0.f, alo1 = 0.f, ahi1 = 0.f;
        int i = 0;
        for (; i + 16 <= c; i += 16) {
            unsigned p0 = sl[s0 + i +  0 + half], p1 = sl[s0 + i +  2 + half];
            unsigned p2 = sl[s0 + i +  4 + half], p3 = sl[s0 + i +  6 + half];
            unsigned p4 = sl[s0 + i +  8 + half], p5 = sl[s0 + i + 10 + half];
            unsigned p6 = sl[s0 + i + 12 + half], p7 = sl[s0 + i + 14 + half];
            unsigned v0 = Xu[(size_t)(p0 & 0xFFFFFFu) * 32 + c2];
            unsigned v1 = Xu[(size_t)(p1 & 0xFFFFFFu) * 32 + c2];
            unsigned v2 = Xu[(size_t)(p2 & 0xFFFFFFu) * 32 + c2];
            unsigned v3 = Xu[(size_t)(p3 & 0xFFFFFFu) * 32 + c2];
            unsigned v4 = Xu[(size_t)(p4 & 0xFFFFFFu) * 32 + c2];
            unsigned v5 = Xu[(size_t)(p5 & 0xFFFFFFu) * 32 + c2];
            unsigned v6 = Xu[(size_t)(p6 & 0xFFFFFFu) * 32 + c2];
            unsigned v7 = Xu[(size_t)(p7 & 0xFFFFFFu) * 32 + c2];
            alo0 += blo2f(v0); ahi0 += bhi2f(v0);
            alo1 += blo2f(v1); ahi1 += bhi2f(v1);
            alo0 += blo2f(v2); ahi0 += bhi2f(v2);
            alo1 += blo2f(v3); ahi1 += bhi2f(v3);
            alo0 += blo2f(v4); ahi0 += bhi2f(v4);
            alo1 += blo2f(v5); ahi1 += bhi2f(v5);
            alo0 += blo2f(v6); ahi0 += bhi2f(v6);
            alo1 += blo2f(v7); ahi1 += bhi2f(v7);
        }
        for (; i + 2 <= c; i += 2) {
            unsigned p = sl[s0 + i + half];
            unsigned v = Xu[(size_t)(p & 0xFFFFFFu) * 32 + c2];
            alo0 += blo2f(v); ahi0 += bhi2f(v);
        }
        if (i + half < c) {            // odd tail (half 0 lanes only)
            unsigned p = sl[s0 + i + half];
            unsigned v = Xu[(size_t)(p & 0xFFFFFFu) * 32 + c2];
            alo1 += blo2f(v); ahi1 += bhi2f(v);
        }
        float alo = alo0 + alo1;
        float ahi = ahi0 + ahi1;
        float xlo = __shfl(alo, lane + 32);
        float xhi = __shfl(ahi, lane + 32);
        if (half == 0) {
            alo += xlo; ahi += xhi;
            ((unsigned*)agg_s)[n * (APITCH / 2) + c2] =
                (unsigned)f2b(alo) | ((unsigned)f2b(ahi) << 16);
        }
    }
    __syncthreads();   // agg tile complete; sl dead -> scratch becomes h_s

    // ---- Phase 2: MLP on the 64 owned nodes ----
    // Frag maps (verified): A[m=lane&15][k=quad*8+j], B[k=quad*8+j][n=lane&15],
    // D[m=quad*4+r][n=lane&15]
    int row  = lane & 15;
    int quad = lane >> 4;
    int mloc = wave * 16 + row;        // local node for A rows

    const ushort_t* ap = agg_s + mloc * APITCH;
    short8 a0 = *(const short8*)(ap + quad * 8);
    short8 a1 = *(const short8*)(ap + 32 + quad * 8);

    float4v zero = {0.f, 0.f, 0.f, 0.f};
    float4v acc[8];
#pragma unroll
    for (int nt = 0; nt < 8; ++nt) acc[nt] = zero;

#pragma unroll
    for (int nt = 0; nt < 8; ++nt) {
        const ushort_t* wp = W1 + (size_t)(nt * 16 + row) * 64 + quad * 8;
        short8 bf0 = *(const short8*)(wp);
        short8 bf1 = *(const short8*)(wp + 32);
        acc[nt] = __builtin_amdgcn_mfma_f32_16x16x32_bf16(a0, bf0, acc[nt], 0, 0, 0);
        acc[nt] = __builtin_amdgcn_mfma_f32_16x16x32_bf16(a1, bf1, acc[nt], 0, 0, 0);
    }

    ushort_t* hw = h_s + wave * 16 * HPITCH;
#pragma unroll
    for (int nt = 0; nt < 8; ++nt) {
        float bias = b1[nt * 16 + row];
#pragma unroll
        for (int r = 0; r < 4; ++r) {
            float v = acc[nt][r] + bias;
            v = v > 0.f ? v : 0.f;
            hw[(quad * 4 + r) * HPITCH + nt * 16 + row] = f2b(v);
        }
    }
    __syncthreads();

    short8 a2[4];
#pragma unroll
    for (int kt = 0; kt < 4; ++kt)
        a2[kt] = *(const short8*)(hw + row * HPITCH + kt * 32 + quad * 8);

    float4v acc2[4];
#pragma unroll
    for (int nt = 0; nt < 4; ++nt) acc2[nt] = zero;

#pragma unroll
    for (int nt = 0; nt < 4; ++nt) {
#pragma unroll
        for (int kt = 0; kt < 4; ++kt) {
            short8 bfr = *(const short8*)(W2 + (size_t)(nt * 16 + row) * 128 +
                                          kt * 32 + quad * 8);
            acc2[nt] = __builtin_amdgcn_mfma_f32_16x16x32_bf16(a2[kt], bfr, acc2[nt], 0, 0, 0);
        }
    }

    int node = lo + wave * 16 + quad * 4;   // N % 4 == 0 => node<N implies +3<N
    if (node < N) {
#pragma unroll
        for (int nt = 0; nt < 4; ++nt) {
            int ko = nt * 16 + row;
            float bias = b2[ko];
            float4v pk;
#pragma unroll
            for (int r = 0; r < 4; ++r) pk[r] = acc2[nt][r] + bias;
            *(float4v*)(out + (size_t)ko * N + node) = pk;
        }
    }
}

// ---------------------------------------------------------------------------
extern "C" void kernel_launch(void* const* d_in, const int* in_sizes, int n_in,
                              void* d_out, int out_size, void* d_ws, size_t ws_size,
                              hipStream_t stream) {
    const float* inp = (const float*)d_in[0];   // [64][N] fp32
    const int*   src = (const int*)d_in[1];
    const int*   dst = (const int*)d_in[2];
    const float* W1  = (const float*)d_in[3];   // [128][64] fp32
    const float* b1  = (const float*)d_in[4];   // [128] fp32
    const float* W2  = (const float*)d_in[5];   // [64][128] fp32
    const float* b2  = (const float*)d_in[6];   // [64] fp32
    float* out = (float*)d_out;                 // [64][N] fp32

    int N  = in_sizes[0] / 64;
    int E  = in_sizes[1];
    int NB = (N + BUCKW - 1) >> BSH;            // 1563 for N=100000 (<= NBMAX)

    // ws: bin u32[NB*CAP] (9.6 MB) + w1b/w2b bf16 (32 KB) + gcur int[NBMAX]
    unsigned* bin  = (unsigned*)d_ws;
    ushort_t* w1b  = (ushort_t*)((char*)d_ws + (size_t)NBMAX * CAP * 4);
    ushort_t* w2b  = w1b + 8192;
    int*      gcur = (int*)(w2b + 8192);

    // X bf16[N*64] staged in d_out first half; consumed by baggmlp_k's gather
    // phase before its MLP phase overwrites d_out (stream-ordered per block?
    // No — X reads all happen in baggmlp phase 1, writes in phase 2 of the
    // SAME kernel. Block A phase 2 may overwrite X while block B is in phase
    // 1!  => X must NOT alias d_out. Place X in ws instead.
    ushort_t* X = (ushort_t*)(gcur + NBMAX);    // +12.8 MB (ws total ~22.5 MB)

    int tb = (N + 63) / 64;
    transpose_k<<<tb, 256, 0, stream>>>(inp, X, N, W1, W2, w1b, w2b, gcur, NB);
    bin_k<<<128, 1024, 0, stream>>>(src, dst, gcur, bin, E, NB);
    baggmlp_k<<<NB, 256, 0, stream>>>((const unsigned*)X, bin, gcur,
                                      w1b, b1, w2b, b2, out, N);
}